// Round 13
// baseline (709.858 us; speedup 1.0000x reference)
//
#include <hip/hip_runtime.h>

#define H     512
#define THD   768
#define MDIM  256
#define NE    16000
#define NU    2000
#define NI    4000
#define NNZ   40000
#define KTOP  10
#define NBATCH 64
#define NEDGE 60000          // NNZ + NU*KTOP
#define GAMA  0.1f
#define P2N   12288          // NL*NB*H
#define PROMPT_N 786432      // 24*64*512
#define NLOSSB 2048

__device__ __forceinline__ float sigmoidf(float x){ return 1.0f/(1.0f+expf(-x)); }
__device__ __forceinline__ float4 f4z(){ return make_float4(0.f,0.f,0.f,0.f); }

// async global->LDS, 16B per lane; LDS dest must be wave-uniform base + lane*16
__device__ __forceinline__ void gll16(const float* g, float* l){
  __builtin_amdgcn_global_load_lds(
      (const __attribute__((address_space(1))) void*)g,
      (__attribute__((address_space(3))) void*)l, 16, 0, 0);
}

// ---------- gm directly from group-mean of token embeds (linearity of GEMM) ----------
// gm[b,c] = (mean_j A[j,:]) @ tp_w[:,c] + tp_b[c]
__global__ __launch_bounds__(256) void k_gmd(const int* __restrict__ sysid,
        const float* __restrict__ A, const float* __restrict__ W,
        const float* __restrict__ bias, float* __restrict__ gm){
  __shared__ float ma[THD];
  int b=blockIdx.x, half=blockIdx.y, t=threadIdx.x;
  int sid=sysid[b];
  #pragma unroll
  for(int j3=0;j3<3;j3++){
    int k=t+j3*256;
    float s=0.f, cnt=0.f;
    for(int j=0;j<NBATCH;j++){ if(sysid[j]==sid){ s+=A[j*THD+k]; cnt+=1.f; } }
    ma[k]=s/cnt;
  }
  __syncthreads();
  int c=half*256+t;
  float s=bias[c];
  for(int k=0;k<THD;k++) s+=ma[k]*W[k*H+c];
  gm[b*H+c]=s;
}

// ---------- tiled fp32 GEMM body, BM=BN=64, BK=32, register-prefetch dbuf ----------
template<int EPI, bool NT, bool AIDX>
__device__ __forceinline__ void gemm_body(float (*As)[68], float (*Bs)[68],
        const float* __restrict__ A, const float* __restrict__ Bm,
        const float* __restrict__ bias, const int* __restrict__ aidx,
        float* __restrict__ C, int M, int N, int K, int bx, int by, int t){
  int n0=bx*64, m0=by*64;
  int tn=t&15, tm=t>>4;
  float4 pa[2], pb[2];
  #pragma unroll
  for(int i=0;i<2;i++){
    int idx=t+i*256; int r=idx>>3, q=idx&7;
    int grow=m0+r;
    pa[i]=f4z();
    if(grow<M){
      const float* arow=A+(size_t)(AIDX? aidx[grow]:grow)*K;
      pa[i]=*(const float4*)(arow+q*4);
    }
  }
  #pragma unroll
  for(int i=0;i<2;i++){
    if(!NT){
      int idx=t+i*256; int r=idx>>4, q=idx&15;
      pb[i]=*(const float4*)(Bm+(size_t)r*N+n0+q*4);
    } else {
      int idx=t+i*256; int r=idx>>3, q=idx&7;
      int gn=n0+r;
      pb[i]=f4z();
      if(gn<N) pb[i]=*(const float4*)(Bm+(size_t)gn*K+q*4);
    }
  }
  float acc[4][4]={};
  for(int kt=0;kt<K;kt+=32){
    __syncthreads();
    #pragma unroll
    for(int i=0;i<2;i++){
      int idx=t+i*256; int r=idx>>3, q=idx&7;
      As[q*4+0][r]=pa[i].x; As[q*4+1][r]=pa[i].y; As[q*4+2][r]=pa[i].z; As[q*4+3][r]=pa[i].w;
    }
    #pragma unroll
    for(int i=0;i<2;i++){
      if(!NT){
        int idx=t+i*256; int r=idx>>4, q=idx&15;
        *(float4*)&Bs[r][q*4]=pb[i];
      } else {
        int idx=t+i*256; int r=idx>>3, q=idx&7;
        Bs[q*4+0][r]=pb[i].x; Bs[q*4+1][r]=pb[i].y; Bs[q*4+2][r]=pb[i].z; Bs[q*4+3][r]=pb[i].w;
      }
    }
    __syncthreads();
    if(kt+32<K){
      #pragma unroll
      for(int i=0;i<2;i++){
        int idx=t+i*256; int r=idx>>3, q=idx&7;
        int grow=m0+r;
        pa[i]=f4z();
        if(grow<M){
          const float* arow=A+(size_t)(AIDX? aidx[grow]:grow)*K;
          pa[i]=*(const float4*)(arow+kt+32+q*4);
        }
      }
      #pragma unroll
      for(int i=0;i<2;i++){
        if(!NT){
          int idx=t+i*256; int r=idx>>4, q=idx&15;
          pb[i]=*(const float4*)(Bm+(size_t)(kt+32+r)*N+n0+q*4);
        } else {
          int idx=t+i*256; int r=idx>>3, q=idx&7;
          int gn=n0+r;
          pb[i]=f4z();
          if(gn<N) pb[i]=*(const float4*)(Bm+(size_t)gn*K+kt+32+q*4);
        }
      }
    }
    #pragma unroll 8
    for(int k=0;k<32;k++){
      float4 a4=*(const float4*)&As[k][tm*4];
      float4 b4=*(const float4*)&Bs[k][tn*4];
      acc[0][0]+=a4.x*b4.x; acc[0][1]+=a4.x*b4.y; acc[0][2]+=a4.x*b4.z; acc[0][3]+=a4.x*b4.w;
      acc[1][0]+=a4.y*b4.x; acc[1][1]+=a4.y*b4.y; acc[1][2]+=a4.y*b4.z; acc[1][3]+=a4.y*b4.w;
      acc[2][0]+=a4.z*b4.x; acc[2][1]+=a4.z*b4.y; acc[2][2]+=a4.z*b4.z; acc[2][3]+=a4.z*b4.w;
      acc[3][0]+=a4.w*b4.x; acc[3][1]+=a4.w*b4.y; acc[3][2]+=a4.w*b4.z; acc[3][3]+=a4.w*b4.w;
    }
  }
  #pragma unroll
  for(int bi=0;bi<4;bi++){
    int row=m0+tm*4+bi; if(row>=M) continue;
    #pragma unroll
    for(int ki=0;ki<4;ki++){
      int col=n0+tn*4+ki; if(col>=N) continue;
      float v=acc[bi][ki];
      if(EPI==0){ if(bias) v+=bias[col]; }
      else { v=sigmoidf(v); }
      C[(size_t)row*N+col]=v;
    }
  }
}

template<int EPI, bool NT, bool AIDX>
__global__ __launch_bounds__(256) void k_gemm(const float* __restrict__ A,
        const float* __restrict__ Bm, const float* __restrict__ bias,
        const int* __restrict__ aidx, float* __restrict__ C, int M, int N, int K){
  __shared__ float As[32][68];
  __shared__ float Bs[32][68];
  gemm_body<EPI,NT,AIDX>(As,Bs,A,Bm,bias,aidx,C,M,N,K,blockIdx.x,blockIdx.y,threadIdx.x);
}

// ---------- launchA: front-end slices || urep-base GEMM || irep GEMM ----------
// bid<192: front (which=bid>>6, b=bid&63), 512 thr.
// bid>=192: two 256-thr 64x64 GEMM tiles per block (barrier-aligned halves).
__global__ __launch_bounds__(512) void k_launchA(const int* __restrict__ sysid,
        const float* __restrict__ gm,
        const float* __restrict__ trans_w, const float* __restrict__ trans_b,
        const float* __restrict__ mw1, const float* __restrict__ mb1,
        const float* __restrict__ ue, const float* __restrict__ mb2,
        const float* __restrict__ trt_w, const float* __restrict__ trt_b,
        const float* __restrict__ pa,
        const float* __restrict__ node_emb, const float* __restrict__ sw1,
        const float* __restrict__ sw2, const int* __restrict__ itemid,
        float* __restrict__ hh, float* __restrict__ ueT, float* __restrict__ enh,
        float* __restrict__ usertok, float* __restrict__ urep, float* __restrict__ irep){
  __shared__ float As[2][32][68];
  __shared__ float Bs[2][32][68];
  int bid=blockIdx.x, t=threadIdx.x;
  if(bid<192){
    float* fl=(float*)As;        // 512 floats
    float* hp=((float*)As)+512;  // 512 floats
    int which=bid>>6, b=bid&63;
    if(which==0){
      const float* g=gm+b*H;
      float s=trans_b[t];
      for(int k=0;k<H;k++) s+=g[k]*trans_w[k*H+t];
      float al=pa[0]; float pr=(s>=0.f)? s : al*s;
      fl[t]=pr*g[t];
      __syncthreads();
      int m=t&255, half=t>>8;
      float s2=0.f; int k0=half*256;
      for(int k=0;k<256;k++) s2+=fl[k0+k]*mw1[(k0+k)*MDIM+m];
      hp[t]=s2;
      __syncthreads();
      if(t<256) hh[b*MDIM+t]=fmaxf(hp[t]+hp[t+256]+mb1[t],0.f);
    } else if(which==1){
      const float* u=ue+(size_t)sysid[b]*H;
      float v=u[t];
      ueT[t*64+b]=v;
      float s=0.f;
      for(int h=0;h<H;h++) s+=u[h]*mb2[(size_t)h*H+t];
      enh[b*H+t]=s;
    } else {
      const float* a=gm+b*H; float s=trt_b[t];
      for(int k=0;k<H;k++) s+=a[k]*trt_w[k*H+t];
      float al=pa[0]; float pr=(s>=0.f)? s : al*s;
      usertok[(size_t)sysid[b]*H+t]=pr*gm[b*H+t];
    }
  } else {
    int p=bid-192;
    int h=t>>8, tid=t&255;
    int tile=p*2+h;               // 0..759  -> (bx 0..7, by 0..94)
    int by=tile>>3, bx=tile&7;
    if(by<32)
      gemm_body<0,false,false>(As[h],Bs[h],ue,sw1,nullptr,nullptr,urep,NU,H,H,bx,by,tid);
    else
      gemm_body<0,false,true >(As[h],Bs[h],node_emb,sw2,nullptr,itemid,irep,NI,H,H,bx,by-32,tid);
  }
}

// ---------- big hypernet contraction ----------
// partials[slice=hs*256+m][b][k] = hh[b,m] * sum_{h in hs-half} ueT[h,b]*W2[m,h*H+k]
#define HCH 8
__global__ __launch_bounds__(128) void k_big(const float* __restrict__ hh,
        const float* __restrict__ ueT, const float* __restrict__ w2,
        float* __restrict__ partials){
  __shared__ float a_lds[2][HCH][64];     // 4 KB
  __shared__ float w_lds[2][HCH][256];    // 16 KB
  int m=blockIdx.x;                       // 0..255
  int kt=blockIdx.y&1, hs=blockIdx.y>>1;  // k-half, h-half
  int k0=kt*256;
  int hbase=hs*256;
  int t=threadIdx.x;                      // 0..127
  int kg=t&15, bg=t>>4;                   // 16 k-quads (x4 chunks), 8 b-quads (x2)
  const float* w2m = w2 + (size_t)m*(size_t)(H*H);

  float4 acc[8][4];                       // [b-row][k-chunk], literal-indexed only
  #pragma unroll
  for(int r=0;r<8;r++){
    #pragma unroll
    for(int c=0;c<4;c++) acc[r][c]=f4z();
  }

  #define STAGE(buf,hc) do{                                             \
    int h0=hbase+(hc)*HCH;                                              \
    gll16(ueT + (size_t)(h0+(t>>4))*64 + (t&15)*4,                      \
          &a_lds[buf][t>>4][(t&15)*4]);                                 \
    _Pragma("unroll")                                                   \
    for(int j=0;j<4;j++){                                               \
      int i=t+j*128;                                                    \
      gll16(w2m + (size_t)(h0+(i>>6))*H + k0 + (i&63)*4,                \
            &w_lds[buf][i>>6][(i&63)*4]);                               \
    }                                                                   \
  }while(0)

  STAGE(0,0);
  int cur=0;
  for(int hc=0;hc<32;hc++){
    __syncthreads();
    if(hc<31) STAGE(cur^1,hc+1);
    #pragma unroll
    for(int hl=0;hl<HCH;hl++){
      float4 aL=*(const float4*)&a_lds[cur][hl][bg*4];
      float4 aH=*(const float4*)&a_lds[cur][hl][32+bg*4];
      float4 w0=*(const float4*)&w_lds[cur][hl][kg*4];
      float4 w1=*(const float4*)&w_lds[cur][hl][64+kg*4];
      float4 w2v=*(const float4*)&w_lds[cur][hl][128+kg*4];
      float4 w3=*(const float4*)&w_lds[cur][hl][192+kg*4];
      #define FMA4(ac,av,wv) ac.x+=(av)*wv.x; ac.y+=(av)*wv.y; ac.z+=(av)*wv.z; ac.w+=(av)*wv.w;
      #define ROWC(r,av) FMA4(acc[r][0],av,w0) FMA4(acc[r][1],av,w1) FMA4(acc[r][2],av,w2v) FMA4(acc[r][3],av,w3)
      ROWC(0,aL.x) ROWC(1,aL.y) ROWC(2,aL.z) ROWC(3,aL.w)
      ROWC(4,aH.x) ROWC(5,aH.y) ROWC(6,aH.z) ROWC(7,aH.w)
      #undef ROWC
      #undef FMA4
    }
    cur^=1;
  }
  int slice=hs*256+m;
  #pragma unroll
  for(int r=0;r<8;r++){
    int br=(r<4)? (bg*4+r) : (32+bg*4+(r-4));
    float hv=hh[br*MDIM+m];
    float* p=partials+((size_t)slice*NBATCH+br)*H+k0+kg*4;
    *(float4*)(p)    =make_float4(acc[r][0].x*hv,acc[r][0].y*hv,acc[r][0].z*hv,acc[r][0].w*hv);
    *(float4*)(p+64) =make_float4(acc[r][1].x*hv,acc[r][1].y*hv,acc[r][1].z*hv,acc[r][1].w*hv);
    *(float4*)(p+128)=make_float4(acc[r][2].x*hv,acc[r][2].y*hv,acc[r][2].z*hv,acc[r][2].w*hv);
    *(float4*)(p+192)=make_float4(acc[r][3].x*hv,acc[r][3].y*hv,acc[r][3].z*hv,acc[r][3].w*hv);
  }
  #undef STAGE
}

// ---------- red1 (4096 blocks) || rownorm of urep-base/irep (6000 blocks) ----------
__global__ __launch_bounds__(256) void k_red1n(const float* __restrict__ partials,
        float* __restrict__ partial2, float* __restrict__ urep, float* __restrict__ irep){
  __shared__ float red4[4];
  int bid=blockIdx.x, t=threadIdx.x;
  if(bid<4096){
    int idx=bid*256+t;                 // 0..1048575
    int g=idx>>15, col=idx&32767;
    const float* p=partials+(size_t)g*16*32768+col;
    float s=0.f;
    #pragma unroll
    for(int m=0;m<16;m++) s+=p[(size_t)m*32768];
    partial2[idx]=s;
  } else {
    int r=bid-4096;                    // 0..5999
    float* X=(r<NU)? urep+(size_t)r*H : irep+(size_t)(r-NU)*H;
    float v1=X[t], v2=X[t+256];
    float ss=v1*v1+v2*v2;
    for(int o=32;o;o>>=1) ss+=__shfl_xor(ss,o);
    if((t&63)==0) red4[t>>6]=ss;
    __syncthreads();
    float tot=red4[0]+red4[1]+red4[2]+red4[3];
    float nrm=fmaxf(sqrtf(tot),1e-12f);
    X[t]=v1/nrm; X[t+256]=v2/nrm;
  }
}

// ---------- red2 + alltok scatter + urep patch (enh rows) + patch rownorm ----------
__global__ __launch_bounds__(512) void k_red2p(const int* __restrict__ sysid,
        const float* __restrict__ partial2, const float* __restrict__ enh,
        const float* __restrict__ sw1, float* __restrict__ alltok,
        float* __restrict__ urep){
  __shared__ float ef[512];
  __shared__ float rn[8];
  int b=blockIdx.x, t=threadIdx.x;
  int idx=b*512+t;
  float s=enh[idx];
  #pragma unroll
  for(int g=0;g<32;g++) s+=partial2[(size_t)g*32768+idx];
  ef[t]=s;
  int uid=sysid[b];
  alltok[(size_t)uid*H+t]=s;           // duplicate sysids write identical values
  __syncthreads();
  float uv=0.f;
  for(int k=0;k<H;k++) uv+=ef[k]*sw1[k*H+t];   // ascending k == GEMM order
  float ss=uv*uv;
  for(int o=32;o;o>>=1) ss+=__shfl_xor(ss,o);
  if((t&63)==0) rn[t>>6]=ss;
  __syncthreads();
  float tot=rn[0]+rn[1]+rn[2]+rn[3]+rn[4]+rn[5]+rn[6]+rn[7];
  float nrm=fmaxf(sqrtf(tot),1e-12f);
  urep[(size_t)uid*H+t]=uv/nrm;
}

// ---------- 128x256-tile sim GEMM, 8x8/thread (split-quad), reg-prefetch ----------
__global__ __launch_bounds__(512) void k_gemm_sim(const float* __restrict__ A,
        const float* __restrict__ Bm, float* __restrict__ C, int M, int N){
  __shared__ float As[32][132];
  __shared__ float Bs[32][260];
  int n0=blockIdx.x*256, m0=blockIdx.y*128;
  int t=threadIdx.x;
  int tn=t&31, tm=t>>5;
  float4 pa[2], pb[4];
  #pragma unroll
  for(int i=0;i<2;i++){
    int idx=t+i*512; int r=idx>>3, q=idx&7;
    pa[i]=f4z();
    if(m0+r<M) pa[i]=*(const float4*)(A+(size_t)(m0+r)*H+q*4);
  }
  #pragma unroll
  for(int i=0;i<4;i++){
    int idx=t+i*512; int r=idx>>3, q=idx&7;
    pb[i]=f4z();
    if(n0+r<N) pb[i]=*(const float4*)(Bm+(size_t)(n0+r)*H+q*4);
  }
  float4 acc[8][2];
  #pragma unroll
  for(int r=0;r<8;r++){ acc[r][0]=f4z(); acc[r][1]=f4z(); }
  for(int kt=0;kt<H;kt+=32){
    __syncthreads();
    #pragma unroll
    for(int i=0;i<2;i++){
      int idx=t+i*512; int r=idx>>3, q=idx&7;
      As[q*4+0][r]=pa[i].x; As[q*4+1][r]=pa[i].y; As[q*4+2][r]=pa[i].z; As[q*4+3][r]=pa[i].w;
    }
    #pragma unroll
    for(int i=0;i<4;i++){
      int idx=t+i*512; int r=idx>>3, q=idx&7;
      Bs[q*4+0][r]=pb[i].x; Bs[q*4+1][r]=pb[i].y; Bs[q*4+2][r]=pb[i].z; Bs[q*4+3][r]=pb[i].w;
    }
    __syncthreads();
    if(kt+32<H){
      #pragma unroll
      for(int i=0;i<2;i++){
        int idx=t+i*512; int r=idx>>3, q=idx&7;
        pa[i]=f4z();
        if(m0+r<M) pa[i]=*(const float4*)(A+(size_t)(m0+r)*H+kt+32+q*4);
      }
      #pragma unroll
      for(int i=0;i<4;i++){
        int idx=t+i*512; int r=idx>>3, q=idx&7;
        pb[i]=f4z();
        if(n0+r<N) pb[i]=*(const float4*)(Bm+(size_t)(n0+r)*H+kt+32+q*4);
      }
    }
    #pragma unroll 8
    for(int k=0;k<32;k++){
      float4 a0=*(const float4*)&As[k][tm*4];
      float4 a1=*(const float4*)&As[k][64+tm*4];
      float4 b0=*(const float4*)&Bs[k][tn*4];
      float4 b1=*(const float4*)&Bs[k][128+tn*4];
      #define FMA4(ac,av,bv) ac.x+=(av)*bv.x; ac.y+=(av)*bv.y; ac.z+=(av)*bv.z; ac.w+=(av)*bv.w;
      #define ROW(r,av) FMA4(acc[r][0],av,b0) FMA4(acc[r][1],av,b1)
      ROW(0,a0.x) ROW(1,a0.y) ROW(2,a0.z) ROW(3,a0.w)
      ROW(4,a1.x) ROW(5,a1.y) ROW(6,a1.z) ROW(7,a1.w)
      #undef ROW
      #undef FMA4
    }
  }
  #pragma unroll
  for(int r=0;r<8;r++){
    int row=m0+((r<4)? (tm*4+r) : (64+tm*4+(r-4)));
    if(row>=M) continue;
    #pragma unroll
    for(int c=0;c<2;c++){
      int col0=n0+c*128+tn*4;
      float vv[4]={acc[r][c].x,acc[r][c].y,acc[r][c].z,acc[r][c].w};
      #pragma unroll
      for(int j=0;j<4;j++){
        int col=col0+j;
        if(col<N) C[(size_t)row*N+col]=sigmoidf(vv[j]);
      }
    }
  }
}

// ---------- top-k (lax.top_k semantics), register-resident values ----------
__global__ __launch_bounds__(256) void k_topk(const float* __restrict__ sim,
        float* __restrict__ tv, int* __restrict__ ti){
  __shared__ float rv[4];
  __shared__ int   ri[4];
  int u=blockIdx.x, t=threadIdx.x;
  float v[16];
  #pragma unroll
  for(int j=0;j<16;j++){
    int gi=t+j*256;
    v[j]=(gi<NI)? sim[(size_t)u*NI+gi] : -1e30f;
  }
  for(int k=0;k<KTOP;k++){
    float bv=-1e30f; int bi=1<<30;
    #pragma unroll
    for(int j=0;j<16;j++){
      int gi=t+j*256;
      if(v[j]>bv){ bv=v[j]; bi=gi; }   // ascending gi: strict > keeps smallest index on ties
    }
    #pragma unroll
    for(int o=32;o;o>>=1){
      float ov=__shfl_xor(bv,o); int oi=__shfl_xor(bi,o);
      if(ov>bv || (ov==bv && oi<bi)){ bv=ov; bi=oi; }
    }
    if((t&63)==0){ rv[t>>6]=bv; ri[t>>6]=bi; }
    __syncthreads();
    float fv=rv[0]; int fi=ri[0];
    #pragma unroll
    for(int w=1;w<4;w++){
      float ov=rv[w]; int oi=ri[w];
      if(ov>fv || (ov==fv && oi<fi)){ fv=ov; fi=oi; }
    }
    if(t==0){ tv[u*KTOP+k]=fv; ti[u*KTOP+k]=fi; }
    int jj=fi>>8, tt=fi&255;
    #pragma unroll
    for(int j=0;j<16;j++) if(tt==t && j==jj) v[j]=-1e30f;
    __syncthreads();
  }
}

// ---------- edges, CSR, normalizers ----------
__global__ void k_edges(const int* __restrict__ adj_row, const int* __restrict__ adj_col,
        const float* __restrict__ adj_val, const int* __restrict__ itemid,
        const float* __restrict__ tv, const int* __restrict__ ti,
        int* __restrict__ rows, int* __restrict__ cols, float* __restrict__ vals,
        float* __restrict__ seg_r, float* __restrict__ seg_c,
        int* __restrict__ row_cnt, int* __restrict__ col_cnt, int* __restrict__ inv){
  int e=blockIdx.x*256+threadIdx.x; if(e>=NEDGE) return;
  if(e<NI) inv[itemid[e]]=e;                 // inv scatter (memset -1 done earlier)
  int r,c; float v;
  if(e<NNZ){ r=adj_row[e]; c=adj_col[e]; v=adj_val[e]; }
  else { int x=e-NNZ; int u=x/KTOP; r=u; c=itemid[ti[x]]; v=tv[x]; }
  rows[e]=r; cols[e]=c; vals[e]=v;
  atomicAdd(&seg_r[r],v); atomicAdd(&seg_c[c],v);
  atomicAdd(&row_cnt[r],1); atomicAdd(&col_cnt[c],1);
}

__global__ __launch_bounds__(1024) void k_scan(const int* __restrict__ rc, int* __restrict__ rp,
        const int* __restrict__ cc, int* __restrict__ cp){
  const int* cnt; int* ptr; int n;
  if(blockIdx.x==0){ cnt=rc; ptr=rp; n=NU; } else { cnt=cc; ptr=cp; n=NE; }
  int t=threadIdx.x;
  int chunk=(n+1023)>>10;
  int base=t*chunk;
  int s=0;
  for(int i=0;i<chunk;i++){ int j=base+i; if(j<n) s+=cnt[j]; }
  __shared__ int buf[1024];
  buf[t]=s; __syncthreads();
  for(int off=1;off<1024;off<<=1){
    int y=(t>=off)? buf[t-off]:0;
    __syncthreads();
    buf[t]+=y;
    __syncthreads();
  }
  int run=buf[t]-s;
  for(int i=0;i<chunk;i++){ int j=base+i; if(j<n){ ptr[j]=run; run+=cnt[j]; } }
  if(t==1023) ptr[n]=buf[1023];
}

// fused: CSR fill + v_u/v_i + dense scatter
__global__ void k_fill(const int* __restrict__ rows, const int* __restrict__ cols,
        const float* __restrict__ vals,
        const int* __restrict__ row_ptr, const int* __restrict__ col_ptr,
        const float* __restrict__ seg_r, const float* __restrict__ seg_c,
        int* __restrict__ fr, int* __restrict__ fc,
        int* __restrict__ ebr, int* __restrict__ ebc,
        float* __restrict__ v_u, float* __restrict__ v_i,
        const int* __restrict__ inv, float* __restrict__ dense){
  int e=blockIdx.x*256+threadIdx.x; if(e>=NEDGE) return;
  int r=rows[e], c=cols[e];
  ebr[row_ptr[r]+atomicAdd(&fr[r],1)]=e;
  ebc[col_ptr[c]+atomicAdd(&fc[c],1)]=e;
  v_u[e]=vals[e]/seg_r[r];
  v_i[e]=vals[e]/seg_c[c];
  if(e<NNZ){
    int ic=inv[c];
    if(ic>=0) atomicAdd(&dense[(size_t)r*NI+ic],vals[e]);
  }
}

// ---------- SpMM bodies (device functions, shared passed in) ----------
__device__ __forceinline__ void spmm_u_body(int u, const int* __restrict__ row_ptr,
        const int* __restrict__ ebr, const int* __restrict__ cols,
        const float* __restrict__ v_u, const float* __restrict__ X,
        const float* __restrict__ usertok, float* __restrict__ out,
        int* sc, float* sv, float (*red)[512]){
  int t=threadIdx.x, w=t>>6, l=t&63;
  int s=row_ptr[u], n=row_ptr[u+1]-s;
  float4 a0=f4z(), a1=f4z();
  for(int base=0;base<n;base+=128){
    int cnt=min(n-base,128);
    if(t<cnt){ int e=ebr[s+base+t]; sc[t]=cols[e]; sv[t]=v_u[e]; }
    __syncthreads();
    for(int j=w;j<cnt;j+=4){
      float v=sv[j];
      const float4* xr=(const float4*)(X+(size_t)sc[j]*H);
      float4 x0=xr[l], x1=xr[l+64];
      a0.x+=v*x0.x; a0.y+=v*x0.y; a0.z+=v*x0.z; a0.w+=v*x0.w;
      a1.x+=v*x1.x; a1.y+=v*x1.y; a1.z+=v*x1.z; a1.w+=v*x1.w;
    }
    __syncthreads();
  }
  if(w>0){ *(float4*)&red[w-1][l*4]=a0; *(float4*)&red[w-1][l*4+256]=a1; }
  __syncthreads();
  if(w==0){
    #pragma unroll
    for(int ww=0;ww<3;ww++){
      float4 r0=*(const float4*)&red[ww][l*4], r1=*(const float4*)&red[ww][l*4+256];
      a0.x+=r0.x; a0.y+=r0.y; a0.z+=r0.z; a0.w+=r0.w;
      a1.x+=r1.x; a1.y+=r1.y; a1.z+=r1.z; a1.w+=r1.w;
    }
    const float4* ut=(const float4*)(usertok+(size_t)u*H);
    float4 u0=ut[l], u1=ut[l+64];
    float4* o=(float4*)(out+(size_t)u*H);
    o[l]   =make_float4(a0.x+a0.x*u0.x, a0.y+a0.y*u0.y, a0.z+a0.z*u0.z, a0.w+a0.w*u0.w);
    o[l+64]=make_float4(a1.x+a1.x*u1.x, a1.y+a1.y*u1.y, a1.z+a1.z*u1.z, a1.w+a1.w*u1.w);
  }
}

__device__ __forceinline__ void spmm_i1_body(int ib, const int* __restrict__ col_ptr,
        const int* __restrict__ ebc, const int* __restrict__ rows,
        const float* __restrict__ v_i, const float* __restrict__ alltok,
        const float* __restrict__ usertok, const float* __restrict__ i0,
        float* __restrict__ Att, float* __restrict__ i1){
  int i=ib*4+(threadIdx.x>>6);
  int l=threadIdx.x&63;
  int s=col_ptr[i], e1=col_ptr[i+1];
  float4 aA0=f4z(),aA1=f4z(),aU0=f4z(),aU1=f4z();
  for(int j=s;j<e1;j++){
    int e=ebc[j]; float v=v_i[e]; int r=rows[e];
    const float4* ur=(const float4*)(usertok+(size_t)r*H);
    const float4* ar=(const float4*)(alltok+(size_t)r*H);
    float4 u0=ur[l],u1v=ur[l+64],A0=ar[l],A1=ar[l+64];
    aA0.x+=v*u0.x; aA0.y+=v*u0.y; aA0.z+=v*u0.z; aA0.w+=v*u0.w;
    aA1.x+=v*u1v.x; aA1.y+=v*u1v.y; aA1.z+=v*u1v.z; aA1.w+=v*u1v.w;
    aU0.x+=v*A0.x; aU0.y+=v*A0.y; aU0.z+=v*A0.z; aU0.w+=v*A0.w;
    aU1.x+=v*A1.x; aU1.y+=v*A1.y; aU1.z+=v*A1.z; aU1.w+=v*A1.w;
  }
  size_t o=(size_t)i*128;
  const float4* z=(const float4*)i0;
  float4 z0=z[o+l], z1=z[o+l+64];
  ((float4*)Att)[o+l]   =aA0;
  ((float4*)Att)[o+l+64]=aA1;
  ((float4*)i1)[o+l]   =make_float4(aU0.x+aA0.x*z0.x, aU0.y+aA0.y*z0.y, aU0.z+aA0.z*z0.z, aU0.w+aA0.w*z0.w);
  ((float4*)i1)[o+l+64]=make_float4(aU1.x+aA1.x*z1.x, aU1.y+aA1.y*z1.y, aU1.z+aA1.z*z1.z, aU1.w+aA1.w*z1.w);
}

__device__ __forceinline__ void spmm_i2_body(int ib, const int* __restrict__ col_ptr,
        const int* __restrict__ ebc, const int* __restrict__ rows,
        const float* __restrict__ v_i, const float* __restrict__ u1,
        const float* __restrict__ Att, const float* __restrict__ i1,
        const float* __restrict__ i0, float* __restrict__ item_out){
  int i=ib*4+(threadIdx.x>>6);
  int l=threadIdx.x&63;
  int s=col_ptr[i], e1=col_ptr[i+1];
  float4 a0=f4z(), a1=f4z();
  for(int j=s;j<e1;j++){
    int e=ebc[j]; float v=v_i[e];
    const float4* ur=(const float4*)(u1+(size_t)rows[e]*H);
    float4 x0=ur[l], x1=ur[l+64];
    a0.x+=v*x0.x; a0.y+=v*x0.y; a0.z+=v*x0.z; a0.w+=v*x0.w;
    a1.x+=v*x1.x; a1.y+=v*x1.y; a1.z+=v*x1.z; a1.w+=v*x1.w;
  }
  size_t o=(size_t)i*128;
  float4 A0=((const float4*)Att)[o+l], A1=((const float4*)Att)[o+l+64];
  float4 I0=((const float4*)i1)[o+l],  I1=((const float4*)i1)[o+l+64];
  float4 Z0=((const float4*)i0)[o+l],  Z1=((const float4*)i0)[o+l+64];
  float4 r0=make_float4((Z0.x+I0.x+a0.x+A0.x*I0.x)/3.f,(Z0.y+I0.y+a0.y+A0.y*I0.y)/3.f,
                        (Z0.z+I0.z+a0.z+A0.z*I0.z)/3.f,(Z0.w+I0.w+a0.w+A0.w*I0.w)/3.f);
  float4 r1=make_float4((Z1.x+I1.x+a1.x+A1.x*I1.x)/3.f,(Z1.y+I1.y+a1.y+A1.y*I1.y)/3.f,
                        (Z1.z+I1.z+a1.z+A1.z*I1.z)/3.f,(Z1.w+I1.w+a1.w+A1.w*I1.w)/3.f);
  ((float4*)item_out)[o+l]=r0;
  ((float4*)item_out)[o+l+64]=r1;
}

__device__ __forceinline__ void loss_body(int lb, const float* __restrict__ sim,
        const float* __restrict__ dense, float* __restrict__ acc, float* red){
  int t=threadIdx.x;
  size_t n4=(size_t)NU*NI/4;
  float s=0.f;
  for(size_t i=(size_t)lb*256+t; i<n4; i+=(size_t)NLOSSB*256){
    float4 a=((const float4*)sim)[i], d=((const float4*)dense)[i];
    float dx=a.x-d.x, dy=a.y-d.y, dz=a.z-d.z, dw=a.w-d.w;
    s+=dx*dx+dy*dy+dz*dz+dw*dw;
  }
  red[t]=s; __syncthreads();
  for(int o=128;o;o>>=1){ if(t<o) red[t]+=red[t+o]; __syncthreads(); }
  if(t==0) atomicAdd(acc,red[0]);
}

// stage1: u1 SpMM || i1/Att SpMM || loss reduction (all independent)
__global__ __launch_bounds__(256) void k_stage1(const int* __restrict__ row_ptr,
        const int* __restrict__ ebr, const int* __restrict__ colsA,
        const float* __restrict__ v_u, const float* __restrict__ node_emb,
        const float* __restrict__ usertok, float* __restrict__ u1,
        const int* __restrict__ col_ptr, const int* __restrict__ ebc,
        const int* __restrict__ rowsA, const float* __restrict__ v_i,
        const float* __restrict__ alltok, float* __restrict__ Att, float* __restrict__ i1,
        const float* __restrict__ sim, const float* __restrict__ dense,
        float* __restrict__ loss_acc){
  __shared__ int   sc[128];
  __shared__ float sv[128];
  __shared__ float red[3][512];
  int bid=blockIdx.x;
  if(bid<NU)              spmm_u_body(bid,row_ptr,ebr,colsA,v_u,node_emb,usertok,u1,sc,sv,red);
  else if(bid<NU+NE/4)    spmm_i1_body(bid-NU,col_ptr,ebc,rowsA,v_i,alltok,usertok,node_emb,Att,i1);
  else                    loss_body(bid-(NU+NE/4),sim,dense,loss_acc,(float*)red);
}

// stage2: u2 SpMM || i2/item_out SpMM || loss scalar write (last block)
__global__ __launch_bounds__(256) void k_stage2(const int* __restrict__ row_ptr,
        const int* __restrict__ ebr, const int* __restrict__ colsA,
        const float* __restrict__ v_u, const float* __restrict__ i1,
        const float* __restrict__ usertok, float* __restrict__ u2,
        const int* __restrict__ col_ptr, const int* __restrict__ ebc,
        const int* __restrict__ rowsA, const float* __restrict__ v_i,
        const float* __restrict__ u1, const float* __restrict__ Att,
        const float* __restrict__ node_emb, float* __restrict__ item_out,
        const float* __restrict__ loss_acc, float* __restrict__ out_loss){
  __shared__ int   sc[128];
  __shared__ float sv[128];
  __shared__ float red[3][512];
  int bid=blockIdx.x;
  if(bid<NU) spmm_u_body(bid,row_ptr,ebr,colsA,v_u,i1,usertok,u2,sc,sv,red);
  else if(bid<NU+NE/4) spmm_i2_body(bid-NU,col_ptr,ebc,rowsA,v_i,u1,Att,i1,node_emb,item_out);
  else if(threadIdx.x==0) out_loss[0]=GAMA*(loss_acc[0]/(float)((size_t)NU*NI));
}

// ---------- prompt head: fused sysfin + q + p1 (one block per b) ----------
__global__ __launch_bounds__(512) void k_sysq_p1(const int* __restrict__ sysid,
        const float* __restrict__ u0, const float* __restrict__ u1, const float* __restrict__ u2,
        const float* __restrict__ p1w1, const float* __restrict__ p1b1,
        const float* __restrict__ p1w2, const float* __restrict__ p1b2,
        float* __restrict__ p1buf){
  __shared__ float sf[512];
  __shared__ float hp[512];
  __shared__ float qv[256];
  int b=blockIdx.x, t=threadIdx.x;
  size_t o=(size_t)sysid[b]*H+t;
  float sfv=(u0[o]+u1[o]+u2[o])/3.0f;
  sf[t]=sfv;
  __syncthreads();
  int m=t&255, half=t>>8;
  float s=0.f; int k0=half*256;
  for(int k=0;k<256;k++) s+=sf[k0+k]*p1w1[(k0+k)*MDIM+m];
  hp[t]=s;
  __syncthreads();
  if(t<256) qv[t]=fmaxf(hp[t]+hp[t+256]+p1b1[t],0.f);
  __syncthreads();
  float s2=p1b2[t];
  for(int k=0;k<256;k++) s2+=qv[k]*p1w2[k*H+t];
  p1buf[b*H+t]=s2+sf[t];
}

__global__ void k_perm(const float* __restrict__ p2, float* __restrict__ out){
  int idx=blockIdx.x*256+threadIdx.x;       // 0..786431
  int x=idx&511;
  int b=(idx>>9)&63;
  int c=idx>>15;                            // 0..23
  out[idx]=p2[(size_t)b*P2N+c*512+x];
}

// ---------- host ----------
extern "C" void kernel_launch(void* const* d_in, const int* in_sizes, int n_in,
                              void* d_out, int out_size, void* d_ws, size_t ws_size,
                              hipStream_t stream){
  const int*   sysid   =(const int*)  d_in[0];
  const int*   adj_row =(const int*)  d_in[1];
  const int*   adj_col =(const int*)  d_in[2];
  const int*   itemid  =(const int*)  d_in[3];
  const float* tok_emb =(const float*)d_in[4];
  const float* adj_val =(const float*)d_in[5];
  const float* node_emb=(const float*)d_in[6];
  const float* user_emb=(const float*)d_in[7];
  const float* tp_w    =(const float*)d_in[8];
  const float* tp_b    =(const float*)d_in[9];
  const float* trans_w =(const float*)d_in[10];
  const float* trans_b =(const float*)d_in[11];
  const float* trt_w   =(const float*)d_in[12];
  const float* trt_b   =(const float*)d_in[13];
  const float* mw1     =(const float*)d_in[14];
  const float* mb1     =(const float*)d_in[15];
  const float* mw2     =(const float*)d_in[16];
  const float* mb2     =(const float*)d_in[17];
  const float* sw1     =(const float*)d_in[18];
  const float* sw2     =(const float*)d_in[19];
  const float* p1w1    =(const float*)d_in[20];
  const float* p1b1    =(const float*)d_in[21];
  const float* p1w2    =(const float*)d_in[22];
  const float* p1b2    =(const float*)d_in[23];
  const float* p2w     =(const float*)d_in[24];
  const float* p2b     =(const float*)d_in[25];
  const float* pa      =(const float*)d_in[26];

  float* out_prompt=(float*)d_out;
  float* out_item  =out_prompt+PROMPT_N;
  float* out_loss  =out_item+(size_t)NE*H;

  // workspace arena — all large buffers de-aliased
  char* ws=(char*)d_ws; size_t off=0;
  auto A=[&](size_t bytes)->char*{ char* p=ws+off; off+=(bytes+255)&~(size_t)255; return p; };
  float* gm      =(float*)A((size_t)NBATCH*H*4);
  float* hh      =(float*)A((size_t)NBATCH*MDIM*4);
  float* ueT     =(float*)A((size_t)H*NBATCH*4);
  float* enh     =(float*)A((size_t)NBATCH*H*4);
  float* irep    =(float*)A((size_t)NI*H*4);             // 8 MB
  float* alltok  =(float*)A((size_t)NU*H*4);
  float* urep    =(float*)A((size_t)NU*H*4);
  float* u1      =(float*)A((size_t)NU*H*4);
  float* u2      =(float*)A((size_t)NU*H*4);
  float* partials=(float*)A((size_t)512*NBATCH*H*4);     // 64 MB
  float* partial2=(float*)A((size_t)32*32768*4);         // 4 MB
  float* sim     =(float*)A((size_t)NU*NI*4);            // 32 MB
  float* dense   =(float*)A((size_t)NU*NI*4);            // 32 MB
  float* Att     =(float*)A((size_t)NE*H*4);             // 32.8 MB
  float* i1      =(float*)A((size_t)NE*H*4);             // 32.8 MB
  float* tv      =(float*)A((size_t)NU*KTOP*4);
  int*   ti      =(int*)  A((size_t)NU*KTOP*4);
  int*   rowsA   =(int*)  A((size_t)NEDGE*4);
  int*   colsA   =(int*)  A((size_t)NEDGE*4);
  float* valsA   =(float*)A((size_t)NEDGE*4);
  float* v_u     =(float*)A((size_t)NEDGE*4);
  float* v_i     =(float*)A((size_t)NEDGE*4);
  int*   ebr     =(int*)  A((size_t)NEDGE*4);
  int*   ebc     =(int*)  A((size_t)NEDGE*4);
  int*   row_ptr =(int*)  A((size_t)(NU+1)*4);
  int*   col_ptr =(int*)  A((size_t)(NE+1)*4);
  // contiguous zero block: usertok + seg/cnt/fill counters + loss acc
  size_t zb_bytes=(size_t)NU*H*4 + (size_t)(NU+NE)*4*3 + 256;
  char*  zb      =A(zb_bytes);
  float* usertok =(float*)zb;
  float* seg_r   =usertok+(size_t)NU*H;
  float* seg_c   =seg_r+NU;
  int*   row_cnt =(int*)(seg_c+NE);
  int*   col_cnt =row_cnt+NU;
  int*   fr      =col_cnt+NE;
  int*   fc      =fr+NU;
  float* loss_acc=(float*)(fc+NE);
  int*   inv     =(int*)  A((size_t)NE*4);
  float* p1buf   =(float*)A((size_t)NBATCH*H*4);
  float* p2buf   =(float*)A((size_t)NBATCH*P2N*4);
  (void)ws_size; (void)n_in; (void)in_sizes; (void)out_size;

  // independent init first
  hipMemcpyAsync(alltok,user_emb,(size_t)NU*H*4,hipMemcpyDeviceToDevice,stream);
  hipMemsetAsync(zb,0,zb_bytes,stream);
  hipMemsetAsync(inv,0xFF,(size_t)NE*4,stream);
  hipMemsetAsync(dense,0,(size_t)NU*NI*4,stream);

  // front-end: gm direct (tok eliminated via linearity)
  k_gmd<<<dim3(NBATCH,2),256,0,stream>>>(sysid,tok_emb,tp_w,tp_b,gm);
  // front slices || urep-base GEMM || irep GEMM (two 256-thr tiles per 512-thr block)
  k_launchA<<<192+380,512,0,stream>>>(sysid,gm,trans_w,trans_b,mw1,mb1,
                                      user_emb,mb2,trt_w,trt_b,pa,
                                      node_emb,sw1,sw2,itemid,
                                      hh,ueT,enh,usertok,urep,irep);
  k_big  <<<dim3(256,4),128,0,stream>>>(hh,ueT,mw2,partials);
  // red1 || rownorm of urep-base + irep
  k_red1n<<<4096+NU+NI,256,0,stream>>>(partials,partial2,urep,irep);
  // red2 + alltok scatter + urep patch for enhanced rows (+their rownorm)
  k_red2p<<<NBATCH,512,0,stream>>>(sysid,partial2,enh,sw1,alltok,urep);

  // similarity
  k_gemm_sim<<<dim3(16,16),512,0,stream>>>(urep,irep,sim,NU,NI);
  k_topk<<<NU,256,0,stream>>>(sim,tv,ti);

  // edges + CSR (+inv scatter, +vuvi, +dense scatter)
  k_edges<<<(NEDGE+255)/256,256,0,stream>>>(adj_row,adj_col,adj_val,itemid,tv,ti,
                                            rowsA,colsA,valsA,seg_r,seg_c,row_cnt,col_cnt,inv);
  k_scan<<<2,1024,0,stream>>>(row_cnt,row_ptr,col_cnt,col_ptr);
  k_fill<<<(NEDGE+255)/256,256,0,stream>>>(rowsA,colsA,valsA,row_ptr,col_ptr,seg_r,seg_c,
                                           fr,fc,ebr,ebc,v_u,v_i,inv,dense);

  // stage1: u1 || i1/Att || loss
  k_stage1<<<NU+NE/4+NLOSSB,256,0,stream>>>(row_ptr,ebr,colsA,v_u,node_emb,usertok,u1,
                                            col_ptr,ebc,rowsA,v_i,alltok,Att,i1,
                                            sim,dense,loss_acc);

  // stage2: u2 || i2 -> item output || loss scalar write
  k_stage2<<<NU+NE/4+1,256,0,stream>>>(row_ptr,ebr,colsA,v_u,i1,usertok,u2,
                                       col_ptr,ebc,rowsA,v_i,u1,Att,node_emb,out_item,
                                       loss_acc,out_loss);

  // prompt head
  k_sysq_p1<<<NBATCH,512,0,stream>>>(sysid,alltok,u1,u2,p1w1,p1b1,p1w2,p1b2,p1buf);
  k_gemm<0,false,false><<<dim3(192,1),256,0,stream>>>(p1buf,p2w,p2b,nullptr,p2buf,NBATCH,P2N,H);
  k_perm<<<PROMPT_N/256,256,0,stream>>>(p2buf,out_prompt);
}

// Round 14
// 697.753 us; speedup vs baseline: 1.0173x; 1.0173x over previous
//
#include <hip/hip_runtime.h>

#define H     512
#define THD   768
#define MDIM  256
#define NE    16000
#define NU    2000
#define NI    4000
#define NNZ   40000
#define KTOP  10
#define NBATCH 64
#define NEDGE 60000          // NNZ + NU*KTOP
#define GAMA  0.1f
#define P2N   12288          // NL*NB*H
#define PROMPT_N 786432      // 24*64*512
#define NLOSSB 2048

__device__ __forceinline__ float sigmoidf(float x){ return 1.0f/(1.0f+expf(-x)); }
__device__ __forceinline__ float4 f4z(){ return make_float4(0.f,0.f,0.f,0.f); }

// async global->LDS, 16B per lane; LDS dest must be wave-uniform base + lane*16
__device__ __forceinline__ void gll16(const float* g, float* l){
  __builtin_amdgcn_global_load_lds(
      (const __attribute__((address_space(1))) void*)g,
      (__attribute__((address_space(3))) void*)l, 16, 0, 0);
}

// ---------- small dense kernels (64 rows) ----------
__global__ void k_tok(const float* __restrict__ A, const float* __restrict__ W,
                      const float* __restrict__ bias, float* __restrict__ C){
  int b=blockIdx.x, c=blockIdx.y*256+threadIdx.x;
  const float* a=A+b*THD; float s=bias[c];
  for(int k=0;k<THD;k++) s+=a[k]*W[k*H+c];
  C[b*H+c]=s;
}

__global__ void k_gm(const int* __restrict__ sysid, const float* __restrict__ tok,
                     float* __restrict__ gm){
  int b=blockIdx.x, c=blockIdx.y*256+threadIdx.x;
  int sid=sysid[b]; float s=0.f, cnt=0.f;
  for(int j=0;j<NBATCH;j++){ if(sysid[j]==sid){ s+=tok[j*H+c]; cnt+=1.f; } }
  gm[b*H+c]=s/cnt;
}

// merged front-end: y=0 filthh, y=1 uprep(ueT+enh), y=2 user_tok  (512 thr)
__global__ __launch_bounds__(512) void k_front(const int* __restrict__ sysid,
        const float* __restrict__ gm,
        const float* __restrict__ trans_w, const float* __restrict__ trans_b,
        const float* __restrict__ mw1, const float* __restrict__ mb1,
        const float* __restrict__ ue, const float* __restrict__ mb2,
        const float* __restrict__ trt_w, const float* __restrict__ trt_b,
        const float* __restrict__ pa,
        float* __restrict__ hh, float* __restrict__ ueT, float* __restrict__ enh,
        float* __restrict__ usertok){
  __shared__ float fl[512];
  __shared__ float hp[512];
  int b=blockIdx.x, t=threadIdx.x, which=blockIdx.y;
  if(which==0){
    const float* g=gm+b*H;
    float s=trans_b[t];
    for(int k=0;k<H;k++) s+=g[k]*trans_w[k*H+t];
    float al=pa[0]; float pr=(s>=0.f)? s : al*s;
    fl[t]=pr*g[t];
    __syncthreads();
    int m=t&255, half=t>>8;
    float s2=0.f; int k0=half*256;
    for(int k=0;k<256;k++) s2+=fl[k0+k]*mw1[(k0+k)*MDIM+m];
    hp[t]=s2;
    __syncthreads();
    if(t<256) hh[b*MDIM+t]=fmaxf(hp[t]+hp[t+256]+mb1[t],0.f);
  } else if(which==1){
    const float* u=ue+(size_t)sysid[b]*H;
    float v=u[t];
    ueT[t*64+b]=v;
    float s=0.f;
    for(int h=0;h<H;h++) s+=u[h]*mb2[(size_t)h*H+t];
    enh[b*H+t]=s;
  } else {
    const float* a=gm+b*H; float s=trt_b[t];
    for(int k=0;k<H;k++) s+=a[k]*trt_w[k*H+t];
    float al=pa[0]; float pr=(s>=0.f)? s : al*s;
    usertok[(size_t)sysid[b]*H+t]=pr*gm[b*H+t];
  }
}

// ---------- big hypernet contraction ----------
// partials[slice=hs*256+m][b][k] = hh[b,m] * sum_{h in hs-half} ueT[h,b]*W2[m,h*H+k]
#define HCH 8
__global__ __launch_bounds__(128) void k_big(const float* __restrict__ hh,
        const float* __restrict__ ueT, const float* __restrict__ w2,
        float* __restrict__ partials){
  __shared__ float a_lds[2][HCH][64];     // 4 KB
  __shared__ float w_lds[2][HCH][256];    // 16 KB
  int m=blockIdx.x;                       // 0..255
  int kt=blockIdx.y&1, hs=blockIdx.y>>1;  // k-half, h-half
  int k0=kt*256;
  int hbase=hs*256;
  int t=threadIdx.x;                      // 0..127
  int kg=t&15, bg=t>>4;                   // 16 k-quads (x4 chunks), 8 b-quads (x2)
  const float* w2m = w2 + (size_t)m*(size_t)(H*H);

  float4 acc[8][4];                       // [b-row][k-chunk], literal-indexed only
  #pragma unroll
  for(int r=0;r<8;r++){
    #pragma unroll
    for(int c=0;c<4;c++) acc[r][c]=f4z();
  }

  #define STAGE(buf,hc) do{                                             \
    int h0=hbase+(hc)*HCH;                                              \
    gll16(ueT + (size_t)(h0+(t>>4))*64 + (t&15)*4,                      \
          &a_lds[buf][t>>4][(t&15)*4]);                                 \
    _Pragma("unroll")                                                   \
    for(int j=0;j<4;j++){                                               \
      int i=t+j*128;                                                    \
      gll16(w2m + (size_t)(h0+(i>>6))*H + k0 + (i&63)*4,                \
            &w_lds[buf][i>>6][(i&63)*4]);                               \
    }                                                                   \
  }while(0)

  STAGE(0,0);
  int cur=0;
  for(int hc=0;hc<32;hc++){
    __syncthreads();
    if(hc<31) STAGE(cur^1,hc+1);
    #pragma unroll
    for(int hl=0;hl<HCH;hl++){
      float4 aL=*(const float4*)&a_lds[cur][hl][bg*4];
      float4 aH=*(const float4*)&a_lds[cur][hl][32+bg*4];
      float4 w0=*(const float4*)&w_lds[cur][hl][kg*4];
      float4 w1=*(const float4*)&w_lds[cur][hl][64+kg*4];
      float4 w2v=*(const float4*)&w_lds[cur][hl][128+kg*4];
      float4 w3=*(const float4*)&w_lds[cur][hl][192+kg*4];
      #define FMA4(ac,av,wv) ac.x+=(av)*wv.x; ac.y+=(av)*wv.y; ac.z+=(av)*wv.z; ac.w+=(av)*wv.w;
      #define ROWC(r,av) FMA4(acc[r][0],av,w0) FMA4(acc[r][1],av,w1) FMA4(acc[r][2],av,w2v) FMA4(acc[r][3],av,w3)
      ROWC(0,aL.x) ROWC(1,aL.y) ROWC(2,aL.z) ROWC(3,aL.w)
      ROWC(4,aH.x) ROWC(5,aH.y) ROWC(6,aH.z) ROWC(7,aH.w)
      #undef ROWC
      #undef FMA4
    }
    cur^=1;
  }
  int slice=hs*256+m;
  #pragma unroll
  for(int r=0;r<8;r++){
    int br=(r<4)? (bg*4+r) : (32+bg*4+(r-4));
    float hv=hh[br*MDIM+m];
    float* p=partials+((size_t)slice*NBATCH+br)*H+k0+kg*4;
    *(float4*)(p)    =make_float4(acc[r][0].x*hv,acc[r][0].y*hv,acc[r][0].z*hv,acc[r][0].w*hv);
    *(float4*)(p+64) =make_float4(acc[r][1].x*hv,acc[r][1].y*hv,acc[r][1].z*hv,acc[r][1].w*hv);
    *(float4*)(p+128)=make_float4(acc[r][2].x*hv,acc[r][2].y*hv,acc[r][2].z*hv,acc[r][2].w*hv);
    *(float4*)(p+192)=make_float4(acc[r][3].x*hv,acc[r][3].y*hv,acc[r][3].z*hv,acc[r][3].w*hv);
  }
  #undef STAGE
}

// reduce 512 slices -> 32 groups of 16 (stage1, no LDS -> full occupancy)
__global__ void k_red1(const float* __restrict__ partials, float* __restrict__ partial2){
  int idx=blockIdx.x*256+threadIdx.x;      // 0..1048575
  int g=idx>>15, col=idx&32767;
  const float* p=partials+(size_t)g*16*32768+col;
  float s=0.f;
  #pragma unroll
  for(int m=0;m<16;m++) s+=p[(size_t)m*32768];
  partial2[idx]=s;
}
__global__ void k_red2s(const int* __restrict__ sysid, const float* __restrict__ partial2,
                        const float* __restrict__ enh, float* __restrict__ alltok){
  int idx=blockIdx.x*256+threadIdx.x;      // 0..32767
  int b=idx>>9, k=idx&511;
  float s=enh[idx];
  #pragma unroll
  for(int g=0;g<32;g++) s+=partial2[(size_t)g*32768+idx];
  alltok[(size_t)sysid[b]*H+k]=s;          // duplicate sysids write identical values
}

// ---------- tiled fp32 GEMM body, BM=BN=64, BK=32, register-prefetch dbuf ----------
template<int EPI, bool NT, bool AIDX>
__device__ __forceinline__ void gemm_body(float (*As)[68], float (*Bs)[68],
        const float* __restrict__ A, const float* __restrict__ Bm,
        const float* __restrict__ bias, const int* __restrict__ aidx,
        float* __restrict__ C, int M, int N, int K, int bx, int by){
  int n0=bx*64, m0=by*64;
  int t=threadIdx.x;
  int tn=t&15, tm=t>>4;
  float4 pa[2], pb[2];
  #pragma unroll
  for(int i=0;i<2;i++){
    int idx=t+i*256; int r=idx>>3, q=idx&7;
    int grow=m0+r;
    pa[i]=f4z();
    if(grow<M){
      const float* arow=A+(size_t)(AIDX? aidx[grow]:grow)*K;
      pa[i]=*(const float4*)(arow+q*4);
    }
  }
  #pragma unroll
  for(int i=0;i<2;i++){
    if(!NT){
      int idx=t+i*256; int r=idx>>4, q=idx&15;
      pb[i]=*(const float4*)(Bm+(size_t)r*N+n0+q*4);
    } else {
      int idx=t+i*256; int r=idx>>3, q=idx&7;
      int gn=n0+r;
      pb[i]=f4z();
      if(gn<N) pb[i]=*(const float4*)(Bm+(size_t)gn*K+q*4);
    }
  }
  float acc[4][4]={};
  for(int kt=0;kt<K;kt+=32){
    __syncthreads();
    #pragma unroll
    for(int i=0;i<2;i++){
      int idx=t+i*256; int r=idx>>3, q=idx&7;
      As[q*4+0][r]=pa[i].x; As[q*4+1][r]=pa[i].y; As[q*4+2][r]=pa[i].z; As[q*4+3][r]=pa[i].w;
    }
    #pragma unroll
    for(int i=0;i<2;i++){
      if(!NT){
        int idx=t+i*256; int r=idx>>4, q=idx&15;
        *(float4*)&Bs[r][q*4]=pb[i];
      } else {
        int idx=t+i*256; int r=idx>>3, q=idx&7;
        Bs[q*4+0][r]=pb[i].x; Bs[q*4+1][r]=pb[i].y; Bs[q*4+2][r]=pb[i].z; Bs[q*4+3][r]=pb[i].w;
      }
    }
    __syncthreads();
    if(kt+32<K){
      #pragma unroll
      for(int i=0;i<2;i++){
        int idx=t+i*256; int r=idx>>3, q=idx&7;
        int grow=m0+r;
        pa[i]=f4z();
        if(grow<M){
          const float* arow=A+(size_t)(AIDX? aidx[grow]:grow)*K;
          pa[i]=*(const float4*)(arow+kt+32+q*4);
        }
      }
      #pragma unroll
      for(int i=0;i<2;i++){
        if(!NT){
          int idx=t+i*256; int r=idx>>4, q=idx&15;
          pb[i]=*(const float4*)(Bm+(size_t)(kt+32+r)*N+n0+q*4);
        } else {
          int idx=t+i*256; int r=idx>>3, q=idx&7;
          int gn=n0+r;
          pb[i]=f4z();
          if(gn<N) pb[i]=*(const float4*)(Bm+(size_t)gn*K+kt+32+q*4);
        }
      }
    }
    #pragma unroll 8
    for(int k=0;k<32;k++){
      float4 a4=*(const float4*)&As[k][tm*4];
      float4 b4=*(const float4*)&Bs[k][tn*4];
      acc[0][0]+=a4.x*b4.x; acc[0][1]+=a4.x*b4.y; acc[0][2]+=a4.x*b4.z; acc[0][3]+=a4.x*b4.w;
      acc[1][0]+=a4.y*b4.x; acc[1][1]+=a4.y*b4.y; acc[1][2]+=a4.y*b4.z; acc[1][3]+=a4.y*b4.w;
      acc[2][0]+=a4.z*b4.x; acc[2][1]+=a4.z*b4.y; acc[2][2]+=a4.z*b4.z; acc[2][3]+=a4.z*b4.w;
      acc[3][0]+=a4.w*b4.x; acc[3][1]+=a4.w*b4.y; acc[3][2]+=a4.w*b4.z; acc[3][3]+=a4.w*b4.w;
    }
  }
  #pragma unroll
  for(int bi=0;bi<4;bi++){
    int row=m0+tm*4+bi; if(row>=M) continue;
    #pragma unroll
    for(int ki=0;ki<4;ki++){
      int col=n0+tn*4+ki; if(col>=N) continue;
      float v=acc[bi][ki];
      if(EPI==0){ if(bias) v+=bias[col]; }
      else { v=sigmoidf(v); }
      C[(size_t)row*N+col]=v;
    }
  }
}

template<int EPI, bool NT, bool AIDX>
__global__ __launch_bounds__(256) void k_gemm(const float* __restrict__ A,
        const float* __restrict__ Bm, const float* __restrict__ bias,
        const int* __restrict__ aidx, float* __restrict__ C, int M, int N, int K){
  __shared__ float As[32][68];
  __shared__ float Bs[32][68];
  gemm_body<EPI,NT,AIDX>(As,Bs,A,Bm,bias,aidx,C,M,N,K,blockIdx.x,blockIdx.y);
}

// merged urep+irep GEMM: by<32 -> urep tile, else irep tile (independent work)
__global__ __launch_bounds__(256) void k_gemm_ui(const float* __restrict__ alltok,
        const float* __restrict__ node_emb, const float* __restrict__ sw1,
        const float* __restrict__ sw2, const int* __restrict__ itemid,
        float* __restrict__ urep, float* __restrict__ irep){
  __shared__ float As[32][68];
  __shared__ float Bs[32][68];
  if(blockIdx.y<32)
    gemm_body<0,false,false>(As,Bs,alltok,sw1,nullptr,nullptr,urep,NU,H,H,blockIdx.x,blockIdx.y);
  else
    gemm_body<0,false,true >(As,Bs,node_emb,sw2,nullptr,itemid,irep,NI,H,H,blockIdx.x,blockIdx.y-32);
}

// ---------- 128x256-tile sim GEMM, 8x8/thread (split-quad), reg-prefetch ----------
__global__ __launch_bounds__(512) void k_gemm_sim(const float* __restrict__ A,
        const float* __restrict__ Bm, float* __restrict__ C, int M, int N){
  __shared__ float As[32][132];
  __shared__ float Bs[32][260];
  int n0=blockIdx.x*256, m0=blockIdx.y*128;
  int t=threadIdx.x;
  int tn=t&31, tm=t>>5;
  float4 pa[2], pb[4];
  #pragma unroll
  for(int i=0;i<2;i++){
    int idx=t+i*512; int r=idx>>3, q=idx&7;
    pa[i]=f4z();
    if(m0+r<M) pa[i]=*(const float4*)(A+(size_t)(m0+r)*H+q*4);
  }
  #pragma unroll
  for(int i=0;i<4;i++){
    int idx=t+i*512; int r=idx>>3, q=idx&7;
    pb[i]=f4z();
    if(n0+r<N) pb[i]=*(const float4*)(Bm+(size_t)(n0+r)*H+q*4);
  }
  float4 acc[8][2];
  #pragma unroll
  for(int r=0;r<8;r++){ acc[r][0]=f4z(); acc[r][1]=f4z(); }
  for(int kt=0;kt<H;kt+=32){
    __syncthreads();
    #pragma unroll
    for(int i=0;i<2;i++){
      int idx=t+i*512; int r=idx>>3, q=idx&7;
      As[q*4+0][r]=pa[i].x; As[q*4+1][r]=pa[i].y; As[q*4+2][r]=pa[i].z; As[q*4+3][r]=pa[i].w;
    }
    #pragma unroll
    for(int i=0;i<4;i++){
      int idx=t+i*512; int r=idx>>3, q=idx&7;
      Bs[q*4+0][r]=pb[i].x; Bs[q*4+1][r]=pb[i].y; Bs[q*4+2][r]=pb[i].z; Bs[q*4+3][r]=pb[i].w;
    }
    __syncthreads();
    if(kt+32<H){
      #pragma unroll
      for(int i=0;i<2;i++){
        int idx=t+i*512; int r=idx>>3, q=idx&7;
        pa[i]=f4z();
        if(m0+r<M) pa[i]=*(const float4*)(A+(size_t)(m0+r)*H+kt+32+q*4);
      }
      #pragma unroll
      for(int i=0;i<4;i++){
        int idx=t+i*512; int r=idx>>3, q=idx&7;
        pb[i]=f4z();
        if(n0+r<N) pb[i]=*(const float4*)(Bm+(size_t)(n0+r)*H+kt+32+q*4);
      }
    }
    #pragma unroll 8
    for(int k=0;k<32;k++){
      float4 a0=*(const float4*)&As[k][tm*4];
      float4 a1=*(const float4*)&As[k][64+tm*4];
      float4 b0=*(const float4*)&Bs[k][tn*4];
      float4 b1=*(const float4*)&Bs[k][128+tn*4];
      #define FMA4(ac,av,bv) ac.x+=(av)*bv.x; ac.y+=(av)*bv.y; ac.z+=(av)*bv.z; ac.w+=(av)*bv.w;
      #define ROW(r,av) FMA4(acc[r][0],av,b0) FMA4(acc[r][1],av,b1)
      ROW(0,a0.x) ROW(1,a0.y) ROW(2,a0.z) ROW(3,a0.w)
      ROW(4,a1.x) ROW(5,a1.y) ROW(6,a1.z) ROW(7,a1.w)
      #undef ROW
      #undef FMA4
    }
  }
  #pragma unroll
  for(int r=0;r<8;r++){
    int row=m0+((r<4)? (tm*4+r) : (64+tm*4+(r-4)));
    if(row>=M) continue;
    #pragma unroll
    for(int c=0;c<2;c++){
      int col0=n0+c*128+tn*4;
      float vv[4]={acc[r][c].x,acc[r][c].y,acc[r][c].z,acc[r][c].w};
      #pragma unroll
      for(int j=0;j<4;j++){
        int col=col0+j;
        if(col<N) C[(size_t)row*N+col]=sigmoidf(vv[j]);
      }
    }
  }
}

// merged rownorm: r<NU -> urep row, else irep row
__global__ __launch_bounds__(256) void k_rownorm2(float* __restrict__ U, float* __restrict__ I){
  int r=blockIdx.x, t=threadIdx.x;
  float* X=(r<NU)? U+(size_t)r*H : I+(size_t)(r-NU)*H;
  float v1=X[t], v2=X[t+256];
  float ss=v1*v1+v2*v2;
  for(int o=32;o;o>>=1) ss+=__shfl_xor(ss,o);
  __shared__ float red[4];
  if((t&63)==0) red[t>>6]=ss;
  __syncthreads();
  float tot=red[0]+red[1]+red[2]+red[3];
  float nrm=fmaxf(sqrtf(tot),1e-12f);
  X[t]=v1/nrm; X[t+256]=v2/nrm;
}

// ---------- top-k (lax.top_k semantics), register-resident values ----------
__global__ __launch_bounds__(256) void k_topk(const float* __restrict__ sim,
        float* __restrict__ tv, int* __restrict__ ti){
  __shared__ float rv[4];
  __shared__ int   ri[4];
  int u=blockIdx.x, t=threadIdx.x;
  float v[16];
  #pragma unroll
  for(int j=0;j<16;j++){
    int gi=t+j*256;
    v[j]=(gi<NI)? sim[(size_t)u*NI+gi] : -1e30f;
  }
  for(int k=0;k<KTOP;k++){
    float bv=-1e30f; int bi=1<<30;
    #pragma unroll
    for(int j=0;j<16;j++){
      int gi=t+j*256;
      if(v[j]>bv){ bv=v[j]; bi=gi; }   // ascending gi: strict > keeps smallest index on ties
    }
    #pragma unroll
    for(int o=32;o;o>>=1){
      float ov=__shfl_xor(bv,o); int oi=__shfl_xor(bi,o);
      if(ov>bv || (ov==bv && oi<bi)){ bv=ov; bi=oi; }
    }
    if((t&63)==0){ rv[t>>6]=bv; ri[t>>6]=bi; }
    __syncthreads();
    float fv=rv[0]; int fi=ri[0];
    #pragma unroll
    for(int w=1;w<4;w++){
      float ov=rv[w]; int oi=ri[w];
      if(ov>fv || (ov==fv && oi<fi)){ fv=ov; fi=oi; }
    }
    if(t==0){ tv[u*KTOP+k]=fv; ti[u*KTOP+k]=fi; }
    int jj=fi>>8, tt=fi&255;
    #pragma unroll
    for(int j=0;j<16;j++) if(tt==t && j==jj) v[j]=-1e30f;
    __syncthreads();
  }
}

// ---------- edges, CSR, normalizers ----------
__global__ void k_edges(const int* __restrict__ adj_row, const int* __restrict__ adj_col,
        const float* __restrict__ adj_val, const int* __restrict__ itemid,
        const float* __restrict__ tv, const int* __restrict__ ti,
        int* __restrict__ rows, int* __restrict__ cols, float* __restrict__ vals,
        float* __restrict__ seg_r, float* __restrict__ seg_c,
        int* __restrict__ row_cnt, int* __restrict__ col_cnt, int* __restrict__ inv){
  int e=blockIdx.x*256+threadIdx.x; if(e>=NEDGE) return;
  if(e<NI) inv[itemid[e]]=e;                 // inv scatter (memset -1 done earlier)
  int r,c; float v;
  if(e<NNZ){ r=adj_row[e]; c=adj_col[e]; v=adj_val[e]; }
  else { int x=e-NNZ; int u=x/KTOP; r=u; c=itemid[ti[x]]; v=tv[x]; }
  rows[e]=r; cols[e]=c; vals[e]=v;
  atomicAdd(&seg_r[r],v); atomicAdd(&seg_c[c],v);
  atomicAdd(&row_cnt[r],1); atomicAdd(&col_cnt[c],1);
}

__global__ __launch_bounds__(1024) void k_scan(const int* __restrict__ rc, int* __restrict__ rp,
        const int* __restrict__ cc, int* __restrict__ cp){
  const int* cnt; int* ptr; int n;
  if(blockIdx.x==0){ cnt=rc; ptr=rp; n=NU; } else { cnt=cc; ptr=cp; n=NE; }
  int t=threadIdx.x;
  int chunk=(n+1023)>>10;
  int base=t*chunk;
  int s=0;
  for(int i=0;i<chunk;i++){ int j=base+i; if(j<n) s+=cnt[j]; }
  __shared__ int buf[1024];
  buf[t]=s; __syncthreads();
  for(int off=1;off<1024;off<<=1){
    int y=(t>=off)? buf[t-off]:0;
    __syncthreads();
    buf[t]+=y;
    __syncthreads();
  }
  int run=buf[t]-s;
  for(int i=0;i<chunk;i++){ int j=base+i; if(j<n){ ptr[j]=run; run+=cnt[j]; } }
  if(t==1023) ptr[n]=buf[1023];
}

// fused: CSR fill + v_u/v_i + dense scatter
__global__ void k_fill(const int* __restrict__ rows, const int* __restrict__ cols,
        const float* __restrict__ vals,
        const int* __restrict__ row_ptr, const int* __restrict__ col_ptr,
        const float* __restrict__ seg_r, const float* __restrict__ seg_c,
        int* __restrict__ fr, int* __restrict__ fc,
        int* __restrict__ ebr, int* __restrict__ ebc,
        float* __restrict__ v_u, float* __restrict__ v_i,
        const int* __restrict__ inv, float* __restrict__ dense){
  int e=blockIdx.x*256+threadIdx.x; if(e>=NEDGE) return;
  int r=rows[e], c=cols[e];
  ebr[row_ptr[r]+atomicAdd(&fr[r],1)]=e;
  ebc[col_ptr[c]+atomicAdd(&fc[c],1)]=e;
  v_u[e]=vals[e]/seg_r[r];
  v_i[e]=vals[e]/seg_c[c];
  if(e<NNZ){
    int ic=inv[c];
    if(ic>=0) atomicAdd(&dense[(size_t)r*NI+ic],vals[e]);
  }
}

// ---------- SpMM bodies (device functions, shared passed in) ----------
__device__ __forceinline__ void spmm_u_body(int u, const int* __restrict__ row_ptr,
        const int* __restrict__ ebr, const int* __restrict__ cols,
        const float* __restrict__ v_u, const float* __restrict__ X,
        const float* __restrict__ usertok, float* __restrict__ out,
        int* sc, float* sv, float (*red)[512]){
  int t=threadIdx.x, w=t>>6, l=t&63;
  int s=row_ptr[u], n=row_ptr[u+1]-s;
  float4 a0=f4z(), a1=f4z();
  for(int base=0;base<n;base+=128){
    int cnt=min(n-base,128);
    if(t<cnt){ int e=ebr[s+base+t]; sc[t]=cols[e]; sv[t]=v_u[e]; }
    __syncthreads();
    for(int j=w;j<cnt;j+=4){
      float v=sv[j];
      const float4* xr=(const float4*)(X+(size_t)sc[j]*H);
      float4 x0=xr[l], x1=xr[l+64];
      a0.x+=v*x0.x; a0.y+=v*x0.y; a0.z+=v*x0.z; a0.w+=v*x0.w;
      a1.x+=v*x1.x; a1.y+=v*x1.y; a1.z+=v*x1.z; a1.w+=v*x1.w;
    }
    __syncthreads();
  }
  if(w>0){ *(float4*)&red[w-1][l*4]=a0; *(float4*)&red[w-1][l*4+256]=a1; }
  __syncthreads();
  if(w==0){
    #pragma unroll
    for(int ww=0;ww<3;ww++){
      float4 r0=*(const float4*)&red[ww][l*4], r1=*(const float4*)&red[ww][l*4+256];
      a0.x+=r0.x; a0.y+=r0.y; a0.z+=r0.z; a0.w+=r0.w;
      a1.x+=r1.x; a1.y+=r1.y; a1.z+=r1.z; a1.w+=r1.w;
    }
    const float4* ut=(const float4*)(usertok+(size_t)u*H);
    float4 u0=ut[l], u1=ut[l+64];
    float4* o=(float4*)(out+(size_t)u*H);
    o[l]   =make_float4(a0.x+a0.x*u0.x, a0.y+a0.y*u0.y, a0.z+a0.z*u0.z, a0.w+a0.w*u0.w);
    o[l+64]=make_float4(a1.x+a1.x*u1.x, a1.y+a1.y*u1.y, a1.z+a1.z*u1.z, a1.w+a1.w*u1.w);
  }
}

__device__ __forceinline__ void spmm_i1_body(int ib, const int* __restrict__ col_ptr,
        const int* __restrict__ ebc, const int* __restrict__ rows,
        const float* __restrict__ v_i, const float* __restrict__ alltok,
        const float* __restrict__ usertok, const float* __restrict__ i0,
        float* __restrict__ Att, float* __restrict__ i1){
  int i=ib*4+(threadIdx.x>>6);
  int l=threadIdx.x&63;
  int s=col_ptr[i], e1=col_ptr[i+1];
  float4 aA0=f4z(),aA1=f4z(),aU0=f4z(),aU1=f4z();
  for(int j=s;j<e1;j++){
    int e=ebc[j]; float v=v_i[e]; int r=rows[e];
    const float4* ur=(const float4*)(usertok+(size_t)r*H);
    const float4* ar=(const float4*)(alltok+(size_t)r*H);
    float4 u0=ur[l],u1v=ur[l+64],A0=ar[l],A1=ar[l+64];
    aA0.x+=v*u0.x; aA0.y+=v*u0.y; aA0.z+=v*u0.z; aA0.w+=v*u0.w;
    aA1.x+=v*u1v.x; aA1.y+=v*u1v.y; aA1.z+=v*u1v.z; aA1.w+=v*u1v.w;
    aU0.x+=v*A0.x; aU0.y+=v*A0.y; aU0.z+=v*A0.z; aU0.w+=v*A0.w;
    aU1.x+=v*A1.x; aU1.y+=v*A1.y; aU1.z+=v*A1.z; aU1.w+=v*A1.w;
  }
  size_t o=(size_t)i*128;
  const float4* z=(const float4*)i0;
  float4 z0=z[o+l], z1=z[o+l+64];
  ((float4*)Att)[o+l]   =aA0;
  ((float4*)Att)[o+l+64]=aA1;
  ((float4*)i1)[o+l]   =make_float4(aU0.x+aA0.x*z0.x, aU0.y+aA0.y*z0.y, aU0.z+aA0.z*z0.z, aU0.w+aA0.w*z0.w);
  ((float4*)i1)[o+l+64]=make_float4(aU1.x+aA1.x*z1.x, aU1.y+aA1.y*z1.y, aU1.z+aA1.z*z1.z, aU1.w+aA1.w*z1.w);
}

__device__ __forceinline__ void spmm_i2_body(int ib, const int* __restrict__ col_ptr,
        const int* __restrict__ ebc, const int* __restrict__ rows,
        const float* __restrict__ v_i, const float* __restrict__ u1,
        const float* __restrict__ Att, const float* __restrict__ i1,
        const float* __restrict__ i0, float* __restrict__ item_out){
  int i=ib*4+(threadIdx.x>>6);
  int l=threadIdx.x&63;
  int s=col_ptr[i], e1=col_ptr[i+1];
  float4 a0=f4z(), a1=f4z();
  for(int j=s;j<e1;j++){
    int e=ebc[j]; float v=v_i[e];
    const float4* ur=(const float4*)(u1+(size_t)rows[e]*H);
    float4 x0=ur[l], x1=ur[l+64];
    a0.x+=v*x0.x; a0.y+=v*x0.y; a0.z+=v*x0.z; a0.w+=v*x0.w;
    a1.x+=v*x1.x; a1.y+=v*x1.y; a1.z+=v*x1.z; a1.w+=v*x1.w;
  }
  size_t o=(size_t)i*128;
  float4 A0=((const float4*)Att)[o+l], A1=((const float4*)Att)[o+l+64];
  float4 I0=((const float4*)i1)[o+l],  I1=((const float4*)i1)[o+l+64];
  float4 Z0=((const float4*)i0)[o+l],  Z1=((const float4*)i0)[o+l+64];
  float4 r0=make_float4((Z0.x+I0.x+a0.x+A0.x*I0.x)/3.f,(Z0.y+I0.y+a0.y+A0.y*I0.y)/3.f,
                        (Z0.z+I0.z+a0.z+A0.z*I0.z)/3.f,(Z0.w+I0.w+a0.w+A0.w*I0.w)/3.f);
  float4 r1=make_float4((Z1.x+I1.x+a1.x+A1.x*I1.x)/3.f,(Z1.y+I1.y+a1.y+A1.y*I1.y)/3.f,
                        (Z1.z+I1.z+a1.z+A1.z*I1.z)/3.f,(Z1.w+I1.w+a1.w+A1.w*I1.w)/3.f);
  ((float4*)item_out)[o+l]=r0;
  ((float4*)item_out)[o+l+64]=r1;
}

__device__ __forceinline__ void loss_body(int lb, const float* __restrict__ sim,
        const float* __restrict__ dense, float* __restrict__ acc, float* red){
  int t=threadIdx.x;
  size_t n4=(size_t)NU*NI/4;
  float s=0.f;
  for(size_t i=(size_t)lb*256+t; i<n4; i+=(size_t)NLOSSB*256){
    float4 a=((const float4*)sim)[i], d=((const float4*)dense)[i];
    float dx=a.x-d.x, dy=a.y-d.y, dz=a.z-d.z, dw=a.w-d.w;
    s+=dx*dx+dy*dy+dz*dz+dw*dw;
  }
  red[t]=s; __syncthreads();
  for(int o=128;o;o>>=1){ if(t<o) red[t]+=red[t+o]; __syncthreads(); }
  if(t==0) atomicAdd(acc,red[0]);
}

// stage1: u1 SpMM || i1/Att SpMM || loss reduction (all independent)
__global__ __launch_bounds__(256) void k_stage1(const int* __restrict__ row_ptr,
        const int* __restrict__ ebr, const int* __restrict__ colsA,
        const float* __restrict__ v_u, const float* __restrict__ node_emb,
        const float* __restrict__ usertok, float* __restrict__ u1,
        const int* __restrict__ col_ptr, const int* __restrict__ ebc,
        const int* __restrict__ rowsA, const float* __restrict__ v_i,
        const float* __restrict__ alltok, float* __restrict__ Att, float* __restrict__ i1,
        const float* __restrict__ sim, const float* __restrict__ dense,
        float* __restrict__ loss_acc){
  __shared__ int   sc[128];
  __shared__ float sv[128];
  __shared__ float red[3][512];
  int bid=blockIdx.x;
  if(bid<NU)              spmm_u_body(bid,row_ptr,ebr,colsA,v_u,node_emb,usertok,u1,sc,sv,red);
  else if(bid<NU+NE/4)    spmm_i1_body(bid-NU,col_ptr,ebc,rowsA,v_i,alltok,usertok,node_emb,Att,i1);
  else                    loss_body(bid-(NU+NE/4),sim,dense,loss_acc,(float*)red);
}

// stage2: u2 SpMM || i2/item_out SpMM || loss scalar write (last block)
__global__ __launch_bounds__(256) void k_stage2(const int* __restrict__ row_ptr,
        const int* __restrict__ ebr, const int* __restrict__ colsA,
        const float* __restrict__ v_u, const float* __restrict__ i1,
        const float* __restrict__ usertok, float* __restrict__ u2,
        const int* __restrict__ col_ptr, const int* __restrict__ ebc,
        const int* __restrict__ rowsA, const float* __restrict__ v_i,
        const float* __restrict__ u1, const float* __restrict__ Att,
        const float* __restrict__ node_emb, float* __restrict__ item_out,
        const float* __restrict__ loss_acc, float* __restrict__ out_loss){
  __shared__ int   sc[128];
  __shared__ float sv[128];
  __shared__ float red[3][512];
  int bid=blockIdx.x;
  if(bid<NU) spmm_u_body(bid,row_ptr,ebr,colsA,v_u,i1,usertok,u2,sc,sv,red);
  else if(bid<NU+NE/4) spmm_i2_body(bid-NU,col_ptr,ebc,rowsA,v_i,u1,Att,i1,node_emb,item_out);
  else if(threadIdx.x==0) out_loss[0]=GAMA*(loss_acc[0]/(float)((size_t)NU*NI));
}

// ---------- prompt head: fused sysfin + q + p1 (one block per b) ----------
__global__ __launch_bounds__(512) void k_sysq_p1(const int* __restrict__ sysid,
        const float* __restrict__ u0, const float* __restrict__ u1, const float* __restrict__ u2,
        const float* __restrict__ p1w1, const float* __restrict__ p1b1,
        const float* __restrict__ p1w2, const float* __restrict__ p1b2,
        float* __restrict__ p1buf){
  __shared__ float sf[512];
  __shared__ float hp[512];
  __shared__ float qv[256];
  int b=blockIdx.x, t=threadIdx.x;
  size_t o=(size_t)sysid[b]*H+t;
  float sfv=(u0[o]+u1[o]+u2[o])/3.0f;
  sf[t]=sfv;
  __syncthreads();
  int m=t&255, half=t>>8;
  float s=0.f; int k0=half*256;
  for(int k=0;k<256;k++) s+=sf[k0+k]*p1w1[(k0+k)*MDIM+m];
  hp[t]=s;
  __syncthreads();
  if(t<256) qv[t]=fmaxf(hp[t]+hp[t+256]+p1b1[t],0.f);
  __syncthreads();
  float s2=p1b2[t];
  for(int k=0;k<256;k++) s2+=qv[k]*p1w2[k*H+t];
  p1buf[b*H+t]=s2+sf[t];
}

__global__ void k_perm(const float* __restrict__ p2, float* __restrict__ out){
  int idx=blockIdx.x*256+threadIdx.x;       // 0..786431
  int x=idx&511;
  int b=(idx>>9)&63;
  int c=idx>>15;                            // 0..23
  out[idx]=p2[(size_t)b*P2N+c*512+x];
}

// ---------- host ----------
extern "C" void kernel_launch(void* const* d_in, const int* in_sizes, int n_in,
                              void* d_out, int out_size, void* d_ws, size_t ws_size,
                              hipStream_t stream){
  const int*   sysid   =(const int*)  d_in[0];
  const int*   adj_row =(const int*)  d_in[1];
  const int*   adj_col =(const int*)  d_in[2];
  const int*   itemid  =(const int*)  d_in[3];
  const float* tok_emb =(const float*)d_in[4];
  const float* adj_val =(const float*)d_in[5];
  const float* node_emb=(const float*)d_in[6];
  const float* user_emb=(const float*)d_in[7];
  const float* tp_w    =(const float*)d_in[8];
  const float* tp_b    =(const float*)d_in[9];
  const float* trans_w =(const float*)d_in[10];
  const float* trans_b =(const float*)d_in[11];
  const float* trt_w   =(const float*)d_in[12];
  const float* trt_b   =(const float*)d_in[13];
  const float* mw1     =(const float*)d_in[14];
  const float* mb1     =(const float*)d_in[15];
  const float* mw2     =(const float*)d_in[16];
  const float* mb2     =(const float*)d_in[17];
  const float* sw1     =(const float*)d_in[18];
  const float* sw2     =(const float*)d_in[19];
  const float* p1w1    =(const float*)d_in[20];
  const float* p1b1    =(const float*)d_in[21];
  const float* p1w2    =(const float*)d_in[22];
  const float* p1b2    =(const float*)d_in[23];
  const float* p2w     =(const float*)d_in[24];
  const float* p2b     =(const float*)d_in[25];
  const float* pa      =(const float*)d_in[26];

  float* out_prompt=(float*)d_out;
  float* out_item  =out_prompt+PROMPT_N;
  float* out_loss  =out_item+(size_t)NE*H;

  // workspace arena — all large buffers de-aliased
  char* ws=(char*)d_ws; size_t off=0;
  auto A=[&](size_t bytes)->char*{ char* p=ws+off; off+=(bytes+255)&~(size_t)255; return p; };
  float* tok     =(float*)A((size_t)NBATCH*H*4);
  float* gm      =(float*)A((size_t)NBATCH*H*4);
  float* hh      =(float*)A((size_t)NBATCH*MDIM*4);
  float* ueT     =(float*)A((size_t)H*NBATCH*4);
  float* enh     =(float*)A((size_t)NBATCH*H*4);
  float* irep    =(float*)A((size_t)NI*H*4);             // 8 MB
  float* alltok  =(float*)A((size_t)NU*H*4);
  float* urep    =(float*)A((size_t)NU*H*4);
  float* u1      =(float*)A((size_t)NU*H*4);
  float* u2      =(float*)A((size_t)NU*H*4);
  float* partials=(float*)A((size_t)512*NBATCH*H*4);     // 64 MB
  float* partial2=(float*)A((size_t)32*32768*4);         // 4 MB
  float* sim     =(float*)A((size_t)NU*NI*4);            // 32 MB
  float* dense   =(float*)A((size_t)NU*NI*4);            // 32 MB
  float* Att     =(float*)A((size_t)NE*H*4);             // 32.8 MB
  float* i1      =(float*)A((size_t)NE*H*4);             // 32.8 MB
  float* tv      =(float*)A((size_t)NU*KTOP*4);
  int*   ti      =(int*)  A((size_t)NU*KTOP*4);
  int*   rowsA   =(int*)  A((size_t)NEDGE*4);
  int*   colsA   =(int*)  A((size_t)NEDGE*4);
  float* valsA   =(float*)A((size_t)NEDGE*4);
  float* v_u     =(float*)A((size_t)NEDGE*4);
  float* v_i     =(float*)A((size_t)NEDGE*4);
  int*   ebr     =(int*)  A((size_t)NEDGE*4);
  int*   ebc     =(int*)  A((size_t)NEDGE*4);
  int*   row_ptr =(int*)  A((size_t)(NU+1)*4);
  int*   col_ptr =(int*)  A((size_t)(NE+1)*4);
  // contiguous zero block: usertok + seg/cnt/fill counters + loss acc
  size_t zb_bytes=(size_t)NU*H*4 + (size_t)(NU+NE)*4*3 + 256;
  char*  zb      =A(zb_bytes);
  float* usertok =(float*)zb;
  float* seg_r   =usertok+(size_t)NU*H;
  float* seg_c   =seg_r+NU;
  int*   row_cnt =(int*)(seg_c+NE);
  int*   col_cnt =row_cnt+NU;
  int*   fr      =col_cnt+NE;
  int*   fc      =fr+NU;
  float* loss_acc=(float*)(fc+NE);
  int*   inv     =(int*)  A((size_t)NE*4);
  float* p1buf   =(float*)A((size_t)NBATCH*H*4);
  float* p2buf   =(float*)A((size_t)NBATCH*P2N*4);
  (void)ws_size; (void)n_in; (void)in_sizes; (void)out_size;

  // independent init first
  hipMemcpyAsync(alltok,user_emb,(size_t)NU*H*4,hipMemcpyDeviceToDevice,stream);
  hipMemsetAsync(zb,0,zb_bytes,stream);
  hipMemsetAsync(inv,0xFF,(size_t)NE*4,stream);
  hipMemsetAsync(dense,0,(size_t)NU*NI*4,stream);

  // dense front-end
  k_tok  <<<dim3(NBATCH,2),256,0,stream>>>(tok_emb,tp_w,tp_b,tok);
  k_gm   <<<dim3(NBATCH,2),256,0,stream>>>(sysid,tok,gm);
  k_front<<<dim3(NBATCH,3),512,0,stream>>>(sysid,gm,trans_w,trans_b,mw1,mb1,
                                           user_emb,mb2,trt_w,trt_b,pa,
                                           hh,ueT,enh,usertok);
  k_big  <<<dim3(256,4),128,0,stream>>>(hh,ueT,mw2,partials);
  k_red1 <<<4096,256,0,stream>>>(partials,partial2);
  k_red2s<<<128,256,0,stream>>>(sysid,partial2,enh,alltok);

  // similarity (urep+irep in one launch, rownorms in one launch)
  k_gemm_ui<<<dim3(8,95),256,0,stream>>>(alltok,node_emb,sw1,sw2,itemid,urep,irep);
  k_rownorm2<<<NU+NI,256,0,stream>>>(urep,irep);
  k_gemm_sim<<<dim3(16,16),512,0,stream>>>(urep,irep,sim,NU,NI);
  k_topk<<<NU,256,0,stream>>>(sim,tv,ti);

  // edges + CSR (+inv scatter, +vuvi, +dense scatter)
  k_edges<<<(NEDGE+255)/256,256,0,stream>>>(adj_row,adj_col,adj_val,itemid,tv,ti,
                                            rowsA,colsA,valsA,seg_r,seg_c,row_cnt,col_cnt,inv);
  k_scan<<<2,1024,0,stream>>>(row_cnt,row_ptr,col_cnt,col_ptr);
  k_fill<<<(NEDGE+255)/256,256,0,stream>>>(rowsA,colsA,valsA,row_ptr,col_ptr,seg_r,seg_c,
                                           fr,fc,ebr,ebc,v_u,v_i,inv,dense);

  // stage1: u1 || i1/Att || loss
  k_stage1<<<NU+NE/4+NLOSSB,256,0,stream>>>(row_ptr,ebr,colsA,v_u,node_emb,usertok,u1,
                                            col_ptr,ebc,rowsA,v_i,alltok,Att,i1,
                                            sim,dense,loss_acc);

  // stage2: u2 || i2 -> item output || loss scalar write
  k_stage2<<<NU+NE/4+1,256,0,stream>>>(row_ptr,ebr,colsA,v_u,i1,usertok,u2,
                                       col_ptr,ebc,rowsA,v_i,u1,Att,node_emb,out_item,
                                       loss_acc,out_loss);

  // prompt head
  k_sysq_p1<<<NBATCH,512,0,stream>>>(sysid,alltok,u1,u2,p1w1,p1b1,p1w2,p1b2,p1buf);
  k_gemm<0,false,false><<<dim3(192,1),256,0,stream>>>(p1buf,p2w,p2b,nullptr,p2buf,NBATCH,P2N,H);
  k_perm<<<PROMPT_N/256,256,0,stream>>>(p2buf,out_prompt);
}